// Round 4
// baseline (21210.924 us; speedup 1.0000x reference)
//
#include <hip/hip_runtime.h>
#include <stdint.h>

// ---------------------------------------------------------------------------
// TransformerEncoderLayer: b=4 s=2048 d=128 h=8 (head_dim=128) dff=2048
// Round-4: same pure-f32 math as round 3 (which PASSED first validation),
// workspace shrunk 45MB -> 9MB to eliminate suspected d_ws overrun that
// corrupted persistent state across graph replays.
// ---------------------------------------------------------------------------

// C[m][n] = (ACC ? C[m][n] : 0) + sum_k A[m][k] * W[k][n], optional ReLU.
// grid (N/128, M), 128 thr over n. W reads coalesced; A[m][k] broadcast.
template<bool RELU, bool ACC>
__global__ __launch_bounds__(128) void k_gemm(const float* __restrict__ A, int lda,
                                              const float* __restrict__ W, int ldw,
                                              float* __restrict__ C, int ldc,
                                              int K) {
    int n = blockIdx.x * 128 + threadIdx.x;
    int m = blockIdx.y;
    float acc = 0.f;
    for (int k = 0; k < K; ++k)
        acc = fmaf(A[(size_t)m * lda + k], W[(size_t)k * ldw + n], acc);
    if (RELU) acc = fmaxf(acc, 0.f);
    if (ACC) C[(size_t)m * ldc + n] += acc;
    else     C[(size_t)m * ldc + n] = acc;
}

// S[qi][k] = (Q[q0+qi] . K[k]) / sqrt(128); per-head Q,K are [2048][128].
// grid (8, 512), 256 thr; qi = blockIdx.y.
__global__ __launch_bounds__(256) void k_scores(const float* __restrict__ Q,
                                                const float* __restrict__ Kh,
                                                float* __restrict__ S, int q0) {
    int k = blockIdx.x * 256 + threadIdx.x;   // 0..2047
    int q = q0 + blockIdx.y;
    const float* qr = Q + (size_t)q * 128;
    const float* kr = Kh + (size_t)k * 128;
    float acc = 0.f;
    #pragma unroll
    for (int d = 0; d < 128; ++d) acc = fmaf(qr[d], kr[d], acc);
    S[(size_t)blockIdx.y * 2048 + k] = acc * 0.088388347648318447f;
}

// in-place row softmax over ncol; one block (256 thr) per row
__global__ __launch_bounds__(256) void k_softmax(float* __restrict__ S, int ncol) {
    __shared__ float red[256];
    float* row = S + (size_t)blockIdx.x * ncol;
    int t = threadIdx.x;
    float mx = -1e30f;
    for (int j = t; j < ncol; j += 256) mx = fmaxf(mx, row[j]);
    red[t] = mx; __syncthreads();
    for (int s = 128; s > 0; s >>= 1) {
        if (t < s) red[t] = fmaxf(red[t], red[t + s]);
        __syncthreads();
    }
    mx = red[0]; __syncthreads();
    float sum = 0.f;
    for (int j = t; j < ncol; j += 256) {
        float e = __expf(row[j] - mx);
        row[j] = e;
        sum += e;
    }
    red[t] = sum; __syncthreads();
    for (int s = 128; s > 0; s >>= 1) {
        if (t < s) red[t] += red[t + s];
        __syncthreads();
    }
    float inv = 1.f / red[0];
    for (int j = t; j < ncol; j += 256) row[j] *= inv;
}

// ctxh[q0+qi][d] = sum_k S[qi][k] * V[k][d]; per-head V is [2048][128].
// grid 512 (qi), 128 thr (d).
__global__ __launch_bounds__(128) void k_ctx(const float* __restrict__ S,
                                             const float* __restrict__ V,
                                             float* __restrict__ ctxh, int q0) {
    int d = threadIdx.x, qi = blockIdx.x;
    const float* srow = S + (size_t)qi * 2048;
    float acc = 0.f;
    for (int k = 0; k < 2048; ++k)
        acc = fmaf(srow[k], V[(size_t)k * 128 + d], acc);
    ctxh[(size_t)(q0 + qi) * 128 + d] = acc;
}

// out[r] = LayerNorm(base[r] + delta[r]) * g ; one block (128 thr) per row.
// Safe when out == base (each element read/written by exactly one thread).
__global__ __launch_bounds__(128) void k_addln(const float* __restrict__ base,
                                               const float* __restrict__ delta,
                                               const float* __restrict__ g,
                                               float* __restrict__ out) {
    __shared__ float r1[128], r2[128];
    int r = blockIdx.x, t = threadIdx.x;
    float v = base[(size_t)r * 128 + t] + delta[(size_t)r * 128 + t];
    r1[t] = v; r2[t] = v * v; __syncthreads();
    for (int s = 64; s > 0; s >>= 1) {
        if (t < s) { r1[t] += r1[t + s]; r2[t] += r2[t + s]; }
        __syncthreads();
    }
    float mean = r1[0] * (1.f / 128.f);
    float var  = r2[0] * (1.f / 128.f) - mean * mean;
    out[(size_t)r * 128 + t] = (v - mean) * rsqrtf(var + 1e-5f) * g[t];
}

// ---------------------------------------------------------------------------
extern "C" void kernel_launch(void* const* d_in, const int* in_sizes, int n_in,
                              void* d_out, int out_size, void* d_ws, size_t ws_size,
                              hipStream_t stream)
{
    const float* x  = (const float*)d_in[0];
    const float* Wq = (const float*)d_in[1];
    const float* Wk = (const float*)d_in[2];
    const float* Wv = (const float*)d_in[3];
    const float* Wo = (const float*)d_in[4];
    const float* W1 = (const float*)d_in[5];
    const float* W2 = (const float*)d_in[6];
    const float* g1 = (const float*)d_in[7];
    const float* g2 = (const float*)d_in[8];
    float* out = (float*)d_out;
    (void)in_sizes; (void)n_in; (void)out_size; (void)ws_size;

    char* basep = (char*)d_ws;
    size_t off = 0;
    auto carve = [&](size_t bytes) {
        void* q = basep + off;
        off += (bytes + 255) & ~(size_t)255;
        return q;
    };
    // total: 9 MB (+6*256B padding)
    float* Qf   = (float*)carve(2048ull * 128 * 4);   // 1 MB (per-head Q)
    float* Kf   = (float*)carve(2048ull * 128 * 4);   // 1 MB
    float* Vf   = (float*)carve(2048ull * 128 * 4);   // 1 MB
    float* ctxh = (float*)carve(2048ull * 128 * 4);   // 1 MB (per-head ctx)
    float* sab  = (float*)carve(2048ull * 128 * 4);   // 1 MB (accumulated sa)
    float* S    = (float*)carve(512ull * 2048 * 4);   // 4 MB (512-row score chunk)
    float* Hb   = S;                                  // stage-B alias: 512x2048 f32
    float* ffb  = Qf;                                 // stage-B alias: 512x128 f32
    // x1 (post-LN1 activations) lives in d_out rows; rewritten in-place by LN2.

    // ---- stage A: attention + out-proj + LN1, per batch ----
    for (int b = 0; b < 4; ++b) {
        const float* xb = x + (size_t)b * 2048 * 128;
        float* x1b = out + (size_t)b * 2048 * 128;
        for (int h = 0; h < 8; ++h) {
            k_gemm<false, false><<<dim3(1, 2048), 128, 0, stream>>>(
                xb, 128, Wq + h * 128, 1024, Qf, 128, 128);
            k_gemm<false, false><<<dim3(1, 2048), 128, 0, stream>>>(
                xb, 128, Wk + h * 128, 1024, Kf, 128, 128);
            k_gemm<false, false><<<dim3(1, 2048), 128, 0, stream>>>(
                xb, 128, Wv + h * 128, 1024, Vf, 128, 128);
            for (int c = 0; c < 4; ++c) {
                int q0 = c * 512;
                k_scores<<<dim3(8, 512), 256, 0, stream>>>(Qf, Kf, S, q0);
                k_softmax<<<512, 256, 0, stream>>>(S, 2048);
                k_ctx<<<512, 128, 0, stream>>>(S, Vf, ctxh, q0);
            }
            // sa += ctx_h @ Wo[h*128:(h+1)*128, :]
            if (h == 0)
                k_gemm<false, false><<<dim3(1, 2048), 128, 0, stream>>>(
                    ctxh, 128, Wo + (size_t)h * 128 * 128, 128, sab, 128, 128);
            else
                k_gemm<false, true><<<dim3(1, 2048), 128, 0, stream>>>(
                    ctxh, 128, Wo + (size_t)h * 128 * 128, 128, sab, 128, 128);
        }
        k_addln<<<2048, 128, 0, stream>>>(xb, sab, g1, x1b);
    }

    // ---- stage B: FFN + LN2, per batch, 512-row chunks ----
    for (int b = 0; b < 4; ++b) {
        float* x1b = out + (size_t)b * 2048 * 128;
        for (int c = 0; c < 4; ++c) {
            float* xr = x1b + (size_t)c * 512 * 128;
            k_gemm<true, false><<<dim3(16, 512), 128, 0, stream>>>(
                xr, 128, W1, 2048, Hb, 2048, 128);
            k_gemm<false, false><<<dim3(1, 512), 128, 0, stream>>>(
                Hb, 2048, W2, 128, ffb, 128, 2048);
            k_addln<<<512, 128, 0, stream>>>(xr, ffb, g2, xr);
        }
    }
}

// Round 8
// 17029.370 us; speedup vs baseline: 1.2455x; 1.2455x over previous
//
#include <hip/hip_runtime.h>
#include <stdint.h>

// ---------------------------------------------------------------------------
// TransformerEncoderLayer: b=4 s=2048 d=128 h=8 (head_dim=128) dff=2048
// Round-8: round-7 verbatim EXCEPT mfma via __builtin_amdgcn_mfma_f32_16x16x32_bf16
// (hazard-safe: compiler inserts MFMA->VALU wait states; raw asm did not).
// Stage A (attention) = round-4 f32 build VERBATIM (green).
// Stage B (FFN) = MFMA bf16 path under test.
// ---------------------------------------------------------------------------

using f32x4 = __attribute__((ext_vector_type(4))) float;
using s16x8 = __attribute__((ext_vector_type(8))) short;
typedef __bf16 bf16x8 __attribute__((ext_vector_type(8)));

// D = A*B + D. A: lane holds A[lane&15][8*(lane>>4)+e]; B: B[8*(lane>>4)+e][lane&15];
// D: D[(lane>>4)*4+r][lane&15]  (m89/m91-verified layouts)
__device__ inline void mfma_bf16(f32x4* acc, s16x8 a, s16x8 b) {
    *acc = __builtin_amdgcn_mfma_f32_16x16x32_bf16(
        __builtin_bit_cast(bf16x8, a), __builtin_bit_cast(bf16x8, b), *acc, 0, 0, 0);
}

__device__ inline short f2bf(float f) {   // RNE f32 -> bf16 bits
    uint32_t u = __builtin_bit_cast(uint32_t, f);
    u += 0x7fffu + ((u >> 16) & 1u);
    return (short)(u >> 16);
}

// ---------------- round-4 stage-A kernels (GREEN, verbatim) ----------------
template<bool RELU, bool ACC>
__global__ __launch_bounds__(128) void k_gemm(const float* __restrict__ A, int lda,
                                              const float* __restrict__ W, int ldw,
                                              float* __restrict__ C, int ldc,
                                              int K) {
    int n = blockIdx.x * 128 + threadIdx.x;
    int m = blockIdx.y;
    float acc = 0.f;
    for (int k = 0; k < K; ++k)
        acc = fmaf(A[(size_t)m * lda + k], W[(size_t)k * ldw + n], acc);
    if (RELU) acc = fmaxf(acc, 0.f);
    if (ACC) C[(size_t)m * ldc + n] += acc;
    else     C[(size_t)m * ldc + n] = acc;
}

__global__ __launch_bounds__(256) void k_scores(const float* __restrict__ Q,
                                                const float* __restrict__ Kh,
                                                float* __restrict__ S, int q0) {
    int k = blockIdx.x * 256 + threadIdx.x;   // 0..2047
    int q = q0 + blockIdx.y;
    const float* qr = Q + (size_t)q * 128;
    const float* kr = Kh + (size_t)k * 128;
    float acc = 0.f;
    #pragma unroll
    for (int d = 0; d < 128; ++d) acc = fmaf(qr[d], kr[d], acc);
    S[(size_t)blockIdx.y * 2048 + k] = acc * 0.088388347648318447f;
}

__global__ __launch_bounds__(256) void k_softmax(float* __restrict__ S, int ncol) {
    __shared__ float red[256];
    float* row = S + (size_t)blockIdx.x * ncol;
    int t = threadIdx.x;
    float mx = -1e30f;
    for (int j = t; j < ncol; j += 256) mx = fmaxf(mx, row[j]);
    red[t] = mx; __syncthreads();
    for (int s = 128; s > 0; s >>= 1) {
        if (t < s) red[t] = fmaxf(red[t], red[t + s]);
        __syncthreads();
    }
    mx = red[0]; __syncthreads();
    float sum = 0.f;
    for (int j = t; j < ncol; j += 256) {
        float e = __expf(row[j] - mx);
        row[j] = e;
        sum += e;
    }
    red[t] = sum; __syncthreads();
    for (int s = 128; s > 0; s >>= 1) {
        if (t < s) red[t] += red[t + s];
        __syncthreads();
    }
    float inv = 1.f / red[0];
    for (int j = t; j < ncol; j += 256) row[j] *= inv;
}

__global__ __launch_bounds__(128) void k_ctx(const float* __restrict__ S,
                                             const float* __restrict__ V,
                                             float* __restrict__ ctxh, int q0) {
    int d = threadIdx.x, qi = blockIdx.x;
    const float* srow = S + (size_t)qi * 2048;
    float acc = 0.f;
    for (int k = 0; k < 2048; ++k)
        acc = fmaf(srow[k], V[(size_t)k * 128 + d], acc);
    ctxh[(size_t)(q0 + qi) * 128 + d] = acc;
}

__global__ __launch_bounds__(128) void k_addln(const float* __restrict__ base,
                                               const float* __restrict__ delta,
                                               const float* __restrict__ g,
                                               float* __restrict__ out) {
    __shared__ float r1[128], r2[128];
    int r = blockIdx.x, t = threadIdx.x;
    float v = base[(size_t)r * 128 + t] + delta[(size_t)r * 128 + t];
    r1[t] = v; r2[t] = v * v; __syncthreads();
    for (int s = 64; s > 0; s >>= 1) {
        if (t < s) { r1[t] += r1[t + s]; r2[t] += r2[t + s]; }
        __syncthreads();
    }
    float mean = r1[0] * (1.f / 128.f);
    float var  = r2[0] * (1.f / 128.f) - mean * mean;
    out[(size_t)r * 128 + t] = (v - mean) * rsqrtf(var + 1e-5f) * g[t];
}

// ---------------- MFMA stage-B kernels (under test) ------------------------
__global__ __launch_bounds__(256) void k_zero(float* __restrict__ p) {
    p[blockIdx.x * 256 + threadIdx.x] = 0.f;
}

// w [R][C] f32 (C=1<<lc) -> wt [C][R] bf16
__global__ __launch_bounds__(256) void k_transpose_w(const float* __restrict__ w,
                                                     short* __restrict__ wt,
                                                     int R, int lc) {
    int i = blockIdx.x * 256 + threadIdx.x;
    int r = i >> lc, c = i & ((1 << lc) - 1);
    wt[c * R + r] = f2bf(w[i]);
}

// H[1024 chunk][2048] = relu(x1 @ W1); x1 f32, W1T [2048][128] bf16.
__global__ __launch_bounds__(256) void k_ffn1(
    const float* __restrict__ x1, const short* __restrict__ W1T,
    short* __restrict__ H)
{
    const int w = threadIdx.x >> 6, lane = threadIdx.x & 63;
    const int g = lane >> 4, li = lane & 15;
    const int m0 = blockIdx.x * 64 + w * 16;
    const int n0 = blockIdx.y * 64;
    f32x4 acc[4] = {};
    #pragma unroll
    for (int ks = 0; ks < 4; ++ks) {
        const float* xr = x1 + (size_t)(m0 + li) * 128 + ks * 32 + g * 8;
        float4 v0 = *(const float4*)xr, v1 = *(const float4*)(xr + 4);
        s16x8 a = { f2bf(v0.x), f2bf(v0.y), f2bf(v0.z), f2bf(v0.w),
                    f2bf(v1.x), f2bf(v1.y), f2bf(v1.z), f2bf(v1.w) };
        #pragma unroll
        for (int nt = 0; nt < 4; ++nt) {
            s16x8 bfr = *(const s16x8*)(W1T + (size_t)(n0 + nt * 16 + li) * 128
                                            + ks * 32 + g * 8);
            mfma_bf16(&acc[nt], a, bfr);
        }
    }
    #pragma unroll
    for (int nt = 0; nt < 4; ++nt)
        #pragma unroll
        for (int r = 0; r < 4; ++r)
            H[(size_t)(m0 + g * 4 + r) * 2048 + n0 + nt * 16 + li] =
                f2bf(fmaxf(acc[nt][r], 0.f));
}

// C += A[.][k-slice] @ WT^T. A [rows][lda] bf16, WT [128][ldw] bf16,
// C [rows][128] f32 pre-zeroed. grid (rows/32, K/512); 128 thr.
__global__ __launch_bounds__(128) void k_gemmacc(
    const short* __restrict__ A, int lda, const short* __restrict__ WT, int ldw,
    float* __restrict__ C)
{
    const int w = threadIdx.x >> 6, lane = threadIdx.x & 63;
    const int g = lane >> 4, li = lane & 15;
    const int m0 = blockIdx.x * 32 + w * 16;
    const int k0 = blockIdx.y * 512;
    f32x4 acc[8] = {};
    for (int ks = 0; ks < 16; ++ks) {
        s16x8 a = *(const s16x8*)(A + (size_t)(m0 + li) * lda + k0 + ks * 32 + g * 8);
        #pragma unroll
        for (int nt = 0; nt < 8; ++nt) {
            s16x8 bfr = *(const s16x8*)(WT + (size_t)(nt * 16 + li) * ldw
                                           + k0 + ks * 32 + g * 8);
            mfma_bf16(&acc[nt], a, bfr);
        }
    }
    #pragma unroll
    for (int nt = 0; nt < 8; ++nt)
        #pragma unroll
        for (int r = 0; r < 4; ++r)
            atomicAdd(&C[(size_t)(m0 + g * 4 + r) * 128 + nt * 16 + li], acc[nt][r]);
}

// ---------------------------------------------------------------------------
extern "C" void kernel_launch(void* const* d_in, const int* in_sizes, int n_in,
                              void* d_out, int out_size, void* d_ws, size_t ws_size,
                              hipStream_t stream)
{
    const float* x  = (const float*)d_in[0];
    const float* Wq = (const float*)d_in[1];
    const float* Wk = (const float*)d_in[2];
    const float* Wv = (const float*)d_in[3];
    const float* Wo = (const float*)d_in[4];
    const float* W1 = (const float*)d_in[5];
    const float* W2 = (const float*)d_in[6];
    const float* g1 = (const float*)d_in[7];
    const float* g2 = (const float*)d_in[8];
    float* out = (float*)d_out;
    (void)in_sizes; (void)n_in; (void)out_size; (void)ws_size;

    char* basep = (char*)d_ws;
    size_t off = 0;
    auto carve = [&](size_t bytes) {
        void* q = basep + off;
        off += (bytes + 255) & ~(size_t)255;
        return q;
    };
    // ~10 MB total (proven-safe at 9 MB in round 4)
    float* Qf   = (float*)carve(2048ull * 128 * 4);   // 1 MB (per-head Q)
    float* Kf   = (float*)carve(2048ull * 128 * 4);   // 1 MB
    float* Vf   = (float*)carve(2048ull * 128 * 4);   // 1 MB
    float* ctxh = (float*)carve(2048ull * 128 * 4);   // 1 MB
    float* sab  = (float*)carve(2048ull * 128 * 4);   // 1 MB
    float* S    = (float*)carve(512ull * 2048 * 4);   // 4 MB (512-row score chunk)
    short* W1T  = (short*)carve(2048ull * 128 * 2);   // 512 KB
    short* W2T  = (short*)carve(128ull * 2048 * 2);   // 512 KB
    short* H    = (short*)S;                          // stage-B: [1024][2048] bf16 = 4 MB
    float* ffb  = Qf;                                 // stage-B: [2048][128] f32 = 1 MB

    // FFN weight prep (bf16 transposed)
    k_transpose_w<<<1024, 256, 0, stream>>>(W1, W1T, 128, 11);
    k_transpose_w<<<1024, 256, 0, stream>>>(W2, W2T, 2048, 7);

    // ---- stage A: attention + out-proj + LN1, per batch (round-4 verbatim) ----
    for (int b = 0; b < 4; ++b) {
        const float* xb = x + (size_t)b * 2048 * 128;
        float* x1b = out + (size_t)b * 2048 * 128;
        for (int h = 0; h < 8; ++h) {
            k_gemm<false, false><<<dim3(1, 2048), 128, 0, stream>>>(
                xb, 128, Wq + h * 128, 1024, Qf, 128, 128);
            k_gemm<false, false><<<dim3(1, 2048), 128, 0, stream>>>(
                xb, 128, Wk + h * 128, 1024, Kf, 128, 128);
            k_gemm<false, false><<<dim3(1, 2048), 128, 0, stream>>>(
                xb, 128, Wv + h * 128, 1024, Vf, 128, 128);
            for (int c = 0; c < 4; ++c) {
                int q0 = c * 512;
                k_scores<<<dim3(8, 512), 256, 0, stream>>>(Qf, Kf, S, q0);
                k_softmax<<<512, 256, 0, stream>>>(S, 2048);
                k_ctx<<<512, 128, 0, stream>>>(S, Vf, ctxh, q0);
            }
            if (h == 0)
                k_gemm<false, false><<<dim3(1, 2048), 128, 0, stream>>>(
                    ctxh, 128, Wo + (size_t)h * 128 * 128, 128, sab, 128, 128);
            else
                k_gemm<false, true><<<dim3(1, 2048), 128, 0, stream>>>(
                    ctxh, 128, Wo + (size_t)h * 128 * 128, 128, sab, 128, 128);
        }
        k_addln<<<2048, 128, 0, stream>>>(xb, sab, g1, x1b);
    }

    // ---- stage B: FFN + LN2, per batch — MFMA path under test ----
    for (int b = 0; b < 4; ++b) {
        float* x1b = out + (size_t)b * 2048 * 128;
        k_zero<<<1024, 256, 0, stream>>>(ffb);
        for (int c = 0; c < 2; ++c) {
            k_ffn1<<<dim3(16, 32), 256, 0, stream>>>(x1b + (size_t)c * 1024 * 128,
                                                     W1T, H);
            k_gemmacc<<<dim3(32, 4), 128, 0, stream>>>(H, 2048, W2T, 2048,
                                                       ffb + (size_t)c * 1024 * 128);
        }
        k_addln<<<2048, 128, 0, stream>>>(x1b, ffb, g2, x1b);
    }
}

// Round 9
// 1822.010 us; speedup vs baseline: 11.6415x; 9.3465x over previous
//
#include <hip/hip_runtime.h>
#include <stdint.h>

// ---------------------------------------------------------------------------
// TransformerEncoderLayer: b=4 s=2048 d=128 h=8 (head_dim=128) dff=2048
// Round-9: round-6 full-MFMA build with the ONE proven fix: mfma via
// __builtin_amdgcn_mfma_f32_16x16x32_bf16 (raw inline-asm MFMA lacks
// compiler-inserted hazard wait-states -> garbage accumulator reads; r8 A/B).
// Attention core: chunked K staging, row-major V, scalar-gather PV (safe,
// slow variants to be optimized against counters from here).
// ---------------------------------------------------------------------------

using f32x4 = __attribute__((ext_vector_type(4))) float;
using s16x8 = __attribute__((ext_vector_type(8))) short;
typedef __bf16 bf16x8 __attribute__((ext_vector_type(8)));

// D = A*B + D. A: lane holds A[lane&15][8*(lane>>4)+e]; B: B[8*(lane>>4)+e][lane&15];
// D: D[(lane>>4)*4+r][lane&15]  (m89/m91-verified; HW-proven in r8)
__device__ inline void mfma_bf16(f32x4* acc, s16x8 a, s16x8 b) {
    *acc = __builtin_amdgcn_mfma_f32_16x16x32_bf16(
        __builtin_bit_cast(bf16x8, a), __builtin_bit_cast(bf16x8, b), *acc, 0, 0, 0);
}

__device__ inline short f2bf(float f) {   // RNE f32 -> bf16 bits
    uint32_t u = __builtin_bit_cast(uint32_t, f);
    u += 0x7fffu + ((u >> 16) & 1u);
    return (short)(u >> 16);
}

// ---------------- zero an f32 buffer (graph-safe) --------------------------
__global__ __launch_bounds__(256) void k_zero(float* __restrict__ p) {
    p[blockIdx.x * 256 + threadIdx.x] = 0.f;
}

// ---------------- weight transpose: w [R][C] f32 (C=1<<lc) -> wt [C][R] bf16
__global__ __launch_bounds__(256) void k_transpose_w(const float* __restrict__ w,
                                                     short* __restrict__ wt,
                                                     int R, int lc) {
    int i = blockIdx.x * 256 + threadIdx.x;
    int r = i >> lc, c = i & ((1 << lc) - 1);
    wt[c * R + r] = f2bf(w[i]);
}

// ---------------- QKV projection (one batch, one 4-head pass) --------------
// Q,K,V all row-major [hh4][2048][128]. hp = head pass (0/1).
__global__ __launch_bounds__(256) void k_qkv(
    const float* __restrict__ xB, const short* __restrict__ WqT,
    const short* __restrict__ WkT, const short* __restrict__ WvT,
    short* __restrict__ Qh, short* __restrict__ Kh, short* __restrict__ Vh,
    int hp)
{
    const int z = blockIdx.z;
    const short* __restrict__ WT = (z == 0) ? WqT : (z == 1) ? WkT : WvT; // [1024][128]
    short* __restrict__ dst = (z == 0) ? Qh : (z == 1) ? Kh : Vh;
    const int w = threadIdx.x >> 6, lane = threadIdx.x & 63;
    const int g = lane >> 4, li = lane & 15;
    const int m0 = blockIdx.x * 64 + w * 16;
    const int n0 = blockIdx.y * 64;               // 0..448 within the 512-col pass
    f32x4 acc[4] = {};
    #pragma unroll
    for (int ks = 0; ks < 4; ++ks) {
        const float* xr = xB + (size_t)(m0 + li) * 128 + ks * 32 + g * 8;
        float4 v0 = *(const float4*)xr, v1 = *(const float4*)(xr + 4);
        s16x8 a = { f2bf(v0.x), f2bf(v0.y), f2bf(v0.z), f2bf(v0.w),
                    f2bf(v1.x), f2bf(v1.y), f2bf(v1.z), f2bf(v1.w) };
        #pragma unroll
        for (int nt = 0; nt < 4; ++nt) {
            s16x8 bfr = *(const s16x8*)(WT + (size_t)(hp * 512 + n0 + nt * 16 + li) * 128
                                           + ks * 32 + g * 8);
            mfma_bf16(&acc[nt], a, bfr);
        }
    }
    #pragma unroll
    for (int nt = 0; nt < 4; ++nt) {
        int col = n0 + nt * 16 + li;              // 0..511
        int hh = col >> 7, dd = col & 127;        // head-in-pass, dim
        #pragma unroll
        for (int r = 0; r < 4; ++r)
            dst[((size_t)hh * 2048 + m0 + g * 4 + r) * 128 + dd] = f2bf(acc[nt][r]);
    }
}

// ---------------- flash attention (safe core, 128-thr blocks) --------------
// grid (64 qblocks of 32 rows, 4 heads); 2 waves, wave owns 16 q rows, KBLK=64.
// ctx written seq-major [2048][512] (cols = hh*128 + d) for the out-proj GEMM.
__global__ __launch_bounds__(128) void k_attn(
    const short* __restrict__ Qh, const short* __restrict__ Kh,
    const short* __restrict__ Vh, short* __restrict__ ctxp)
{
    __shared__ __align__(16) short Kls[16 * 64 * 8];  // chunked [cc16][row64][e8]
    __shared__ __align__(16) short Vls[64 * 128];     // plain [k][d]
    __shared__ __align__(16) short Pls[2][16 * 64];   // per-wave [q16][k64]
    const int hh = blockIdx.y;
    const size_t base = (size_t)hh * 2048 * 128;
    const int w = threadIdx.x >> 6, lane = threadIdx.x & 63;
    const int g = lane >> 4, li = lane & 15;
    const int q0 = blockIdx.x * 32;
    const int qw = q0 + w * 16;
    const float sc = 0.088388347648318447f; // 1/sqrt(128)

    s16x8 qf[4];
    #pragma unroll
    for (int ks = 0; ks < 4; ++ks)
        qf[ks] = *(const s16x8*)(Qh + base + (size_t)(qw + li) * 128 + ks * 32 + g * 8);

    f32x4 acc[8] = {};
    float mrow[4] = { -1e30f, -1e30f, -1e30f, -1e30f };
    float lrow[4] = { 0.f, 0.f, 0.f, 0.f };

    for (int kt = 0; kt < 32; ++kt) {
        __syncthreads();
        #pragma unroll
        for (int c2 = 0; c2 < 8; ++c2) {
            int ci = threadIdx.x + c2 * 128;       // 0..1023
            int row = ci >> 4, cc = ci & 15;       // coalesced global read
            uint4 kv = *(const uint4*)(Kh + base + (size_t)(kt * 64 + row) * 128 + cc * 8);
            uint4 vv = *(const uint4*)(Vh + base + (size_t)(kt * 64 + row) * 128 + cc * 8);
            *(uint4*)&Kls[(cc * 64 + row) * 8] = kv;   // chunked layout
            *(uint4*)&Vls[row * 128 + cc * 8]  = vv;   // row-major
        }
        __syncthreads();

        // S tile [16 q][64 k] = Q K^T
        f32x4 st[4];
        #pragma unroll
        for (int nt = 0; nt < 4; ++nt) {
            st[nt] = (f32x4){0.f, 0.f, 0.f, 0.f};
            #pragma unroll
            for (int ks = 0; ks < 4; ++ks) {
                s16x8 bfr = *(const s16x8*)&Kls[((ks * 4 + g) * 64 + nt * 16 + li) * 8];
                mfma_bf16(&st[nt], qf[ks], bfr);
            }
        }
        #pragma unroll
        for (int nt = 0; nt < 4; ++nt) st[nt] *= sc;

        // online softmax: row (g*4+r) spread over 16 lanes (li) x 4 regs (nt)
        #pragma unroll
        for (int r = 0; r < 4; ++r) {
            float mx = fmaxf(fmaxf(st[0][r], st[1][r]), fmaxf(st[2][r], st[3][r]));
            mx = fmaxf(mx, __shfl_xor(mx, 1));
            mx = fmaxf(mx, __shfl_xor(mx, 2));
            mx = fmaxf(mx, __shfl_xor(mx, 4));
            mx = fmaxf(mx, __shfl_xor(mx, 8));
            float mnew = fmaxf(mrow[r], mx);
            float alpha = __expf(mrow[r] - mnew);
            float rs = 0.f;
            #pragma unroll
            for (int nt = 0; nt < 4; ++nt) {
                float p = __expf(st[nt][r] - mnew);
                st[nt][r] = p;
                rs += p;
            }
            rs += __shfl_xor(rs, 1);
            rs += __shfl_xor(rs, 2);
            rs += __shfl_xor(rs, 4);
            rs += __shfl_xor(rs, 8);
            lrow[r] = lrow[r] * alpha + rs;
            mrow[r] = mnew;
            #pragma unroll
            for (int dt = 0; dt < 8; ++dt) acc[dt][r] *= alpha;
        }

        // P -> LDS (plain layout), then PV
        short* pw = Pls[w];
        #pragma unroll
        for (int nt = 0; nt < 4; ++nt)
            #pragma unroll
            for (int r = 0; r < 4; ++r)
                pw[(g * 4 + r) * 64 + nt * 16 + li] = f2bf(st[nt][r]);

        #pragma unroll
        for (int kk = 0; kk < 2; ++kk) {
            s16x8 af = *(const s16x8*)&pw[li * 64 + kk * 32 + g * 8];
            #pragma unroll
            for (int dt = 0; dt < 8; ++dt) {
                s16x8 bfr;
                #pragma unroll
                for (int e = 0; e < 8; ++e)   // scalar gather: V[k][d], k varies
                    bfr[e] = Vls[((kk * 4 + g) * 8 + e) * 128 + dt * 16 + li];
                mfma_bf16(&acc[dt], af, bfr);
            }
        }
    }
    #pragma unroll
    for (int r = 0; r < 4; ++r) {
        float inv = 1.f / lrow[r];
        int row = q0 + w * 16 + g * 4 + r;
        #pragma unroll
        for (int dt = 0; dt < 8; ++dt)
            ctxp[(size_t)row * 512 + hh * 128 + dt * 16 + li] =
                f2bf(acc[dt][r] * inv);
    }
}

// ---------------- K-split GEMM accumulate: C += A[.][kslice] @ WT^T --------
// A [rows][lda] bf16, WT [128][ldw] bf16, C [rows][128] f32 (pre-zeroed).
// grid (rows/32, KSLICES); each block does K=512.
__global__ __launch_bounds__(128) void k_gemmacc(
    const short* __restrict__ A, int lda, const short* __restrict__ WT, int ldw,
    float* __restrict__ C)
{
    const int w = threadIdx.x >> 6, lane = threadIdx.x & 63;
    const int g = lane >> 4, li = lane & 15;
    const int m0 = blockIdx.x * 32 + w * 16;
    const int k0 = blockIdx.y * 512;
    f32x4 acc[8] = {};
    for (int ks = 0; ks < 16; ++ks) {
        s16x8 a = *(const s16x8*)(A + (size_t)(m0 + li) * lda + k0 + ks * 32 + g * 8);
        #pragma unroll
        for (int nt = 0; nt < 8; ++nt) {
            s16x8 bfr = *(const s16x8*)(WT + (size_t)(nt * 16 + li) * ldw
                                           + k0 + ks * 32 + g * 8);
            mfma_bf16(&acc[nt], a, bfr);
        }
    }
    #pragma unroll
    for (int nt = 0; nt < 8; ++nt)
        #pragma unroll
        for (int r = 0; r < 4; ++r)
            atomicAdd(&C[(size_t)(m0 + g * 4 + r) * 128 + nt * 16 + li], acc[nt][r]);
}

// ---------------- out[r] = LayerNorm(base[r]+delta[r]) * g (audited) -------
__global__ __launch_bounds__(128) void k_addln(const float* __restrict__ base,
                                               const float* __restrict__ delta,
                                               const float* __restrict__ g,
                                               float* __restrict__ out) {
    __shared__ float r1[128], r2[128];
    int r = blockIdx.x, t = threadIdx.x;
    float v = base[(size_t)r * 128 + t] + delta[(size_t)r * 128 + t];
    r1[t] = v; r2[t] = v * v; __syncthreads();
    for (int s = 64; s > 0; s >>= 1) {
        if (t < s) { r1[t] += r1[t + s]; r2[t] += r2[t + s]; }
        __syncthreads();
    }
    float mean = r1[0] * (1.f / 128.f);
    float var  = r2[0] * (1.f / 128.f) - mean * mean;
    out[(size_t)r * 128 + t] = (v - mean) * rsqrtf(var + 1e-5f) * g[t];
}

// ---------------- FFN1: H = relu(x1 @ W1), 1024-row chunk ------------------
__global__ __launch_bounds__(256) void k_ffn1(
    const float* __restrict__ x1, const short* __restrict__ W1T,
    short* __restrict__ H)
{
    const int w = threadIdx.x >> 6, lane = threadIdx.x & 63;
    const int g = lane >> 4, li = lane & 15;
    const int m0 = blockIdx.x * 64 + w * 16;
    const int n0 = blockIdx.y * 64;
    f32x4 acc[4] = {};
    #pragma unroll
    for (int ks = 0; ks < 4; ++ks) {
        const float* xr = x1 + (size_t)(m0 + li) * 128 + ks * 32 + g * 8;
        float4 v0 = *(const float4*)xr, v1 = *(const float4*)(xr + 4);
        s16x8 a = { f2bf(v0.x), f2bf(v0.y), f2bf(v0.z), f2bf(v0.w),
                    f2bf(v1.x), f2bf(v1.y), f2bf(v1.z), f2bf(v1.w) };
        #pragma unroll
        for (int nt = 0; nt < 4; ++nt) {
            s16x8 bfr = *(const s16x8*)(W1T + (size_t)(n0 + nt * 16 + li) * 128
                                            + ks * 32 + g * 8);
            mfma_bf16(&acc[nt], a, bfr);
        }
    }
    #pragma unroll
    for (int nt = 0; nt < 4; ++nt)
        #pragma unroll
        for (int r = 0; r < 4; ++r)
            H[(size_t)(m0 + g * 4 + r) * 2048 + n0 + nt * 16 + li] =
                f2bf(fmaxf(acc[nt][r], 0.f));
}

// ---------------------------------------------------------------------------
extern "C" void kernel_launch(void* const* d_in, const int* in_sizes, int n_in,
                              void* d_out, int out_size, void* d_ws, size_t ws_size,
                              hipStream_t stream)
{
    const float* x  = (const float*)d_in[0];
    const float* Wq = (const float*)d_in[1];
    const float* Wk = (const float*)d_in[2];
    const float* Wv = (const float*)d_in[3];
    const float* Wo = (const float*)d_in[4];
    const float* W1 = (const float*)d_in[5];
    const float* W2 = (const float*)d_in[6];
    const float* g1 = (const float*)d_in[7];
    const float* g2 = (const float*)d_in[8];
    float* out = (float*)d_out;
    (void)in_sizes; (void)n_in; (void)out_size; (void)ws_size;

    char* basep = (char*)d_ws;
    size_t off = 0;
    auto carve = [&](size_t bytes) {
        void* q = basep + off;
        off += (bytes + 255) & ~(size_t)255;
        return q;
    };
    // total 10.8 MB (proven-safe: 9-10 MB green in r4/r8)
    short* WqT = (short*)carve(1024ull * 128 * 2);       // 256 KB
    short* WkT = (short*)carve(1024ull * 128 * 2);
    short* WvT = (short*)carve(1024ull * 128 * 2);
    short* WoT = (short*)carve(128ull * 1024 * 2);       // 256 KB
    short* W1T = (short*)carve(2048ull * 128 * 2);       // 512 KB
    short* W2T = (short*)carve(128ull * 2048 * 2);       // 512 KB
    short* Qh  = (short*)carve(4ull * 2048 * 128 * 2);   // 2 MB (4 heads/pass)
    short* Kh  = (short*)carve(4ull * 2048 * 128 * 2);   // 2 MB
    short* Vh  = (short*)carve(4ull * 2048 * 128 * 2);   // 2 MB
    short* ctxp= (short*)carve(2048ull * 512 * 2);       // 2 MB [s][512] per pass
    float* sab = (float*)carve(2048ull * 128 * 4);       // 1 MB
    short* H   = Qh;            // FFN1 chunk [1024][2048] bf16 = 4 MB over Qh+Kh
    float* ffb = sab;           // FFN2 accumulator aliases sab

    // weight prep
    k_transpose_w<<<512,  256, 0, stream>>>(Wq, WqT, 128, 10);
    k_transpose_w<<<512,  256, 0, stream>>>(Wk, WkT, 128, 10);
    k_transpose_w<<<512,  256, 0, stream>>>(Wv, WvT, 128, 10);
    k_transpose_w<<<512,  256, 0, stream>>>(Wo, WoT, 1024, 7);
    k_transpose_w<<<1024, 256, 0, stream>>>(W1, W1T, 128, 11);
    k_transpose_w<<<1024, 256, 0, stream>>>(W2, W2T, 2048, 7);

    for (int b = 0; b < 4; ++b) {
        const float* xb = x + (size_t)b * 2048 * 128;
        float* x1b = out + (size_t)b * 2048 * 128;   // x1 lives in d_out rows

        // ---- attention + out-proj ----
        k_zero<<<1024, 256, 0, stream>>>(sab);
        for (int hp = 0; hp < 2; ++hp) {
            k_qkv<<<dim3(32, 8, 3), 256, 0, stream>>>(xb, WqT, WkT, WvT,
                                                      Qh, Kh, Vh, hp);
            k_attn<<<dim3(64, 4), 128, 0, stream>>>(Qh, Kh, Vh, ctxp);
            // sab += ctxp @ Wo[hp*512:(hp+1)*512, :]
            k_gemmacc<<<dim3(64, 1), 128, 0, stream>>>(ctxp, 512,
                                                       WoT + hp * 512, 1024, sab);
        }
        k_addln<<<2048, 128, 0, stream>>>(xb, sab, g1, x1b);

        // ---- FFN ----
        k_zero<<<1024, 256, 0, stream>>>(ffb);
        for (int c = 0; c < 2; ++c) {
            k_ffn1<<<dim3(16, 32), 256, 0, stream>>>(x1b + (size_t)c * 1024 * 128,
                                                     W1T, H);
            k_gemmacc<<<dim3(32, 4), 128, 0, stream>>>(H, 2048, W2T, 2048,
                                                       ffb + (size_t)c * 1024 * 128);
        }
        k_addln<<<2048, 128, 0, stream>>>(x1b, ffb, g2, x1b);
    }
}